// Round 6
// baseline (174.821 us; speedup 1.0000x reference)
//
#include <hip/hip_runtime.h>
#include <math.h>

// Problem constants (fixed by setup_inputs: B=64, C=1, H=512, W=512 fp32)
static constexpr int Hdim = 512;
static constexpr int Wdim = 512;
static constexpr int HW   = Hdim * Wdim;       // 2^18 px per image
static constexpr int NIMG = 64;
static constexpr int WPR  = Wdim / 64;         // 8 uint64 words per row
static constexpr int RSTRIP = 32;              // rows per block strip
static constexpr int SPI  = Hdim / RSTRIP;     // strips per image = 16
static constexpr int NBLK = NIMG * SPI;        // 1024 blocks
static constexpr int MROWS = RSTRIP + 4;       // strip rows + +/-2 halo = 36
static constexpr int NIT = (RSTRIP * Wdim) / (256 * 4);  // 16 phase-3 iters
static constexpr int WORDS_PER_WAVE = (MROWS * WPR) / 4; // 288/4 = 72

// d_ws layout: [0, 32KB): per-block partials (NBLK slots x 8 floats, 5 used)
// No zero-init needed: every partial slot is overwritten each call.

__device__ __forceinline__ unsigned long long shl1(unsigned long long c, unsigned long long l) {
    return (c << 1) | (l >> 63);   // value at x-1
}
__device__ __forceinline__ unsigned long long shr1(unsigned long long c, unsigned long long r) {
    return (c >> 1) | (r << 63);   // value at x+1
}
__device__ __forceinline__ unsigned long long shl2(unsigned long long c, unsigned long long l) {
    return (c << 2) | (l >> 62);
}
__device__ __forceinline__ unsigned long long shr2(unsigned long long c, unsigned long long r) {
    return (c >> 2) | (r << 62);
}

// ---- Fused kernel: ballot-mask + bitwise morphology + elementwise + partials ----
__global__ __launch_bounds__(256) void combined_loss_kernel(
    const float* __restrict__ inp, const float* __restrict__ tgt,
    float* __restrict__ partials)
{
    __shared__ unsigned long long tmask[MROWS][WPR];   // rows r0-2 .. r0+RSTRIP+1
    __shared__ unsigned long long bmask[RSTRIP][WPR];  // boundary bits
    __shared__ float smem[4][5];

    const int img   = blockIdx.x / SPI;
    const int strip = blockIdx.x % SPI;
    const int r0    = strip * RSTRIP;
    const float* ib = inp + img * HW;
    const float* tb = tgt + img * HW;

    const int wave = threadIdx.x >> 6;
    const int lane = threadIdx.x & 63;

    // ---- Phase 1: build target bitmask via coalesced wave ballot, 4-way MLP ----
    // word index wi in [0, 288): row = wi>>3 (0..35), word = wi&7
    unsigned long long* tmflat = &tmask[0][0];
    const int wi_base = wave * WORDS_PER_WAVE;
    #pragma unroll
    for (int g = 0; g < WORDS_PER_WAVE / 4; g++) {   // 18 groups of 4 independent loads
        int wi0 = wi_base + g * 4;
        float v0 = 0.f, v1 = 0.f, v2 = 0.f, v3 = 0.f;
        {
            int gr0 = r0 - 2 + ((wi0 + 0) >> 3);
            int gr1 = r0 - 2 + ((wi0 + 1) >> 3);
            int gr2 = r0 - 2 + ((wi0 + 2) >> 3);
            int gr3 = r0 - 2 + ((wi0 + 3) >> 3);
            if ((unsigned)gr0 < (unsigned)Hdim) v0 = tb[gr0 * Wdim + ((wi0 + 0) & 7) * 64 + lane];
            if ((unsigned)gr1 < (unsigned)Hdim) v1 = tb[gr1 * Wdim + ((wi0 + 1) & 7) * 64 + lane];
            if ((unsigned)gr2 < (unsigned)Hdim) v2 = tb[gr2 * Wdim + ((wi0 + 2) & 7) * 64 + lane];
            if ((unsigned)gr3 < (unsigned)Hdim) v3 = tb[gr3 * Wdim + ((wi0 + 3) & 7) * 64 + lane];
        }
        unsigned long long m0 = __ballot(v0 > 0.5f);
        unsigned long long m1 = __ballot(v1 > 0.5f);
        unsigned long long m2 = __ballot(v2 > 0.5f);
        unsigned long long m3 = __ballot(v3 > 0.5f);
        if (lane == 0) {
            tmflat[wi0 + 0] = m0;
            tmflat[wi0 + 1] = m1;
            tmflat[wi0 + 2] = m2;
            tmflat[wi0 + 3] = m3;
        }
    }
    __syncthreads();

    // ---- Phase 2: boundary = dilate2 & ~erode2 (radius-2 L1 diamond), bitwise ----
    {
        int row  = threadIdx.x >> 3;    // strip row 0..31 (256 threads = 32x8 exactly)
        int word = threadIdx.x & 7;
        int mr = row + 2;

        #define CW(r)  tmask[r][word]
        #define LW(r)  (word > 0 ? tmask[r][word - 1] : 0ULL)
        #define RW(r)  (word < WPR - 1 ? tmask[r][word + 1] : 0ULL)
        unsigned long long c0 = CW(mr),   l0 = LW(mr),   rr0 = RW(mr);
        unsigned long long cm = CW(mr-1), lm = LW(mr-1), rm  = RW(mr-1);
        unsigned long long cp = CW(mr+1), lp = LW(mr+1), rp  = RW(mr+1);
        unsigned long long cm2 = CW(mr-2);
        unsigned long long cp2 = CW(mr+2);
        #undef CW
        #undef LW
        #undef RW

        unsigned long long er =
            c0 & shl1(c0,l0) & shr1(c0,rr0) & shl2(c0,l0) & shr2(c0,rr0)
               & cm & shl1(cm,lm) & shr1(cm,rm)
               & cp & shl1(cp,lp) & shr1(cp,rp)
               & cm2 & cp2;
        unsigned long long di =
            c0 | shl1(c0,l0) | shr1(c0,rr0) | shl2(c0,l0) | shr2(c0,rr0)
               | cm | shl1(cm,lm) | shr1(cm,rm)
               | cp | shl1(cp,lp) | shr1(cp,rp)
               | cm2 | cp2;
        bmask[row][word] = di & ~er;
    }
    __syncthreads();

    // ---- Phase 3: elementwise math, float4 + register prefetch ----
    float s_focal = 0.f, s_inter = 0.f, s_p = 0.f, s_bw = 0.f;
    int s_tc = 0;

    const float* base = ib + r0 * Wdim + threadIdx.x * 4;
    float4 cur = *(const float4*)(base);
    #pragma unroll
    for (int it = 0; it < NIT; it++) {
        float4 nxt;
        if (it + 1 < NIT) nxt = *(const float4*)(base + (it + 1) * 1024);

        int flat = it * 1024 + threadIdx.x * 4;   // px within strip
        int row  = flat >> 9;
        int x    = flat & (Wdim - 1);
        unsigned int tb4 = (unsigned int)((tmask[row + 2][x >> 6] >> (x & 63)) & 0xFULL);
        unsigned int bb4 = (unsigned int)((bmask[row][x >> 6]     >> (x & 63)) & 0xFULL);
        s_tc += __popc(tb4);
        const float xs[4] = {cur.x, cur.y, cur.z, cur.w};
        #pragma unroll
        for (int k = 0; k < 4; k++) {
            float xi = xs[k];
            bool tpos = (tb4 >> k) & 1;
            float e  = __expf(-fabsf(xi));                  // exp(-|x|)
            float bce = fmaxf(xi, 0.f) - (tpos ? xi : 0.f) + __logf(1.f + e);
            float rden = __builtin_amdgcn_rcpf(1.f + e);
            float p = (xi >= 0.f ? 1.f : e) * rden;         // sigmoid
            float pt = tpos ? p : 1.f - p;                  // == exp(-bce)
            float om = 1.f - pt;
            s_focal += 0.25f * om * om * bce;
            s_p     += p;
            s_inter += tpos ? p : 0.f;
            float wgt = ((bb4 >> k) & 1) ? 6.0f : 1.0f;     // 1 + THETA*boundary
            s_bw += bce * wgt;
        }
        cur = nxt;
    }
    float s_t = (float)s_tc;

    // ---- Reduce: wave shuffle -> LDS -> per-block partial store (NO atomics) ----
    #pragma unroll
    for (int off = 32; off > 0; off >>= 1) {
        s_focal += __shfl_down(s_focal, off);
        s_inter += __shfl_down(s_inter, off);
        s_p     += __shfl_down(s_p,     off);
        s_t     += __shfl_down(s_t,     off);
        s_bw    += __shfl_down(s_bw,    off);
    }
    if (lane == 0) {
        smem[wave][0] = s_focal; smem[wave][1] = s_inter; smem[wave][2] = s_p;
        smem[wave][3] = s_t;     smem[wave][4] = s_bw;
    }
    __syncthreads();
    if (threadIdx.x < 5) {
        float a = smem[0][threadIdx.x] + smem[1][threadIdx.x]
                + smem[2][threadIdx.x] + smem[3][threadIdx.x];
        partials[blockIdx.x * 8 + threadIdx.x] = a;
    }
}

// ---- Finalize: reduce 1024 partial slots, compute final scalar ----
__global__ __launch_bounds__(256) void finalize_kernel(
    const float* __restrict__ partials, float* __restrict__ out)
{
    __shared__ float smem[4][5];
    float a0 = 0.f, a1 = 0.f, a2 = 0.f, a3 = 0.f, a4 = 0.f;
    for (int b = threadIdx.x; b < NBLK; b += 256) {
        const float* s = partials + b * 8;
        a0 += s[0]; a1 += s[1]; a2 += s[2]; a3 += s[3]; a4 += s[4];
    }
    #pragma unroll
    for (int off = 32; off > 0; off >>= 1) {
        a0 += __shfl_down(a0, off);
        a1 += __shfl_down(a1, off);
        a2 += __shfl_down(a2, off);
        a3 += __shfl_down(a3, off);
        a4 += __shfl_down(a4, off);
    }
    int wave = threadIdx.x >> 6;
    int lane = threadIdx.x & 63;
    if (lane == 0) {
        smem[wave][0] = a0; smem[wave][1] = a1; smem[wave][2] = a2;
        smem[wave][3] = a3; smem[wave][4] = a4;
    }
    __syncthreads();
    if (threadIdx.x == 0) {
        double b0 = 0, b1 = 0, b2 = 0, b3 = 0, b4 = 0;
        #pragma unroll
        for (int w = 0; w < 4; w++) {
            b0 += smem[w][0]; b1 += smem[w][1]; b2 += smem[w][2];
            b3 += smem[w][3]; b4 += smem[w][4];
        }
        double invN = 1.0 / (double)(NIMG * HW);
        double focal_loss = b0 * invN;
        double dice = (2.0 * b1 + 1e-6) / (b2 + b3 + 1e-6);
        double boundary_loss = b4 * invN;
        out[0] = (float)(0.3 * focal_loss + 0.4 * (1.0 - dice) + 0.3 * boundary_loss);
    }
}

extern "C" void kernel_launch(void* const* d_in, const int* in_sizes, int n_in,
                              void* d_out, int out_size, void* d_ws, size_t ws_size,
                              hipStream_t stream) {
    const float* inp = (const float*)d_in[0];
    const float* tgt = (const float*)d_in[1];
    float* out = (float*)d_out;
    float* partials = (float*)d_ws;

    combined_loss_kernel<<<NBLK, 256, 0, stream>>>(inp, tgt, partials);
    finalize_kernel<<<1, 256, 0, stream>>>(partials, out);
}

// Round 7
// 152.294 us; speedup vs baseline: 1.1479x; 1.1479x over previous
//
#include <hip/hip_runtime.h>
#include <math.h>

// Problem constants (fixed by setup_inputs: B=64, C=1, H=512, W=512 fp32)
static constexpr int Hdim = 512;
static constexpr int Wdim = 512;
static constexpr int HW   = Hdim * Wdim;       // 2^18 px per image
static constexpr int NIMG = 64;
static constexpr int WPR  = Wdim / 64;         // 8 uint64 words per row
static constexpr int WPI  = Hdim * WPR;        // 4096 words per image
static constexpr int TOTAL_WORDS = NIMG * WPI; // 262144 words (2 MB)
static constexpr int NBLK_A = 2048;            // mask kernel blocks
static constexpr int NBLK_B = TOTAL_WORDS / 256;  // 1024 boundary blocks
static constexpr int NBLK_C = 2048;            // main kernel blocks
static constexpr int CTHREADS = NBLK_C * 256;  // 524288
static constexpr int F4TOTAL = NIMG * HW / 4;  // 4194304 float4's
static constexpr int CITERS = F4TOTAL / CTHREADS;  // 8

// d_ws layout:
//   [0, 64KB):          per-block partials (NBLK_C slots x 8 floats, 5 used)
//   [1MB, 3MB):         tmask words (2 MB)
//   [4MB, 8MB):         comb words: interleaved {tword, bword} pairs (4 MB)
// All regions fully overwritten each call; poison-safe.

// ---- Kernel A: pack tgt>0.5 into bitmask, wave-per-word ballot, 4x MLP ----
__global__ __launch_bounds__(256) void mask_kernel(
    const float* __restrict__ tgt, unsigned long long* __restrict__ mask)
{
    const int lane = threadIdx.x & 63;
    const int wid  = (blockIdx.x * 256 + threadIdx.x) >> 6;   // 8192 waves
    #pragma unroll
    for (int g = 0; g < 8; g++) {
        int w0 = wid * 32 + g * 4;
        float v0 = tgt[(w0 + 0) * 64 + lane];
        float v1 = tgt[(w0 + 1) * 64 + lane];
        float v2 = tgt[(w0 + 2) * 64 + lane];
        float v3 = tgt[(w0 + 3) * 64 + lane];
        unsigned long long m0 = __ballot(v0 > 0.5f);
        unsigned long long m1 = __ballot(v1 > 0.5f);
        unsigned long long m2 = __ballot(v2 > 0.5f);
        unsigned long long m3 = __ballot(v3 > 0.5f);
        if (lane == 0) {
            mask[w0 + 0] = m0;
            mask[w0 + 1] = m1;
            mask[w0 + 2] = m2;
            mask[w0 + 3] = m3;
        }
    }
}

__device__ __forceinline__ unsigned long long shl1(unsigned long long c, unsigned long long l) {
    return (c << 1) | (l >> 63);   // value at x-1
}
__device__ __forceinline__ unsigned long long shr1(unsigned long long c, unsigned long long r) {
    return (c >> 1) | (r << 63);   // value at x+1
}
__device__ __forceinline__ unsigned long long shl2(unsigned long long c, unsigned long long l) {
    return (c << 2) | (l >> 62);
}
__device__ __forceinline__ unsigned long long shr2(unsigned long long c, unsigned long long r) {
    return (c >> 2) | (r << 62);
}

// ---- Kernel B: word-parallel morphology; writes interleaved {tword,bword} ----
__global__ __launch_bounds__(256) void boundary_kernel(
    const unsigned long long* __restrict__ mask, unsigned long long* __restrict__ comb)
{
    const int w = blockIdx.x * 256 + threadIdx.x;   // global word id
    const int word = w & 7;                // column-word 0..7
    const int row  = (w >> 3) & (Hdim - 1);
    const unsigned long long* mi = mask + (w & ~(WPI - 1));  // image base

    #define FW(r, c) ((((unsigned)(r)) < (unsigned)Hdim && ((unsigned)(c)) < (unsigned)WPR) \
                        ? mi[((r) << 3) + (c)] : 0ULL)
    unsigned long long c0  = FW(row,     word);
    unsigned long long l0  = FW(row,     word - 1);
    unsigned long long rr0 = FW(row,     word + 1);
    unsigned long long cm  = FW(row - 1, word);
    unsigned long long lm  = FW(row - 1, word - 1);
    unsigned long long rm  = FW(row - 1, word + 1);
    unsigned long long cp  = FW(row + 1, word);
    unsigned long long lp  = FW(row + 1, word - 1);
    unsigned long long rp  = FW(row + 1, word + 1);
    unsigned long long cm2 = FW(row - 2, word);
    unsigned long long cp2 = FW(row + 2, word);
    #undef FW

    unsigned long long er =
        c0 & shl1(c0,l0) & shr1(c0,rr0) & shl2(c0,l0) & shr2(c0,rr0)
           & cm & shl1(cm,lm) & shr1(cm,rm)
           & cp & shl1(cp,lp) & shr1(cp,rp)
           & cm2 & cp2;
    unsigned long long di =
        c0 | shl1(c0,l0) | shr1(c0,rr0) | shl2(c0,l0) | shr2(c0,rr0)
           | cm | shl1(cm,lm) | shr1(cm,rm)
           | cp | shl1(cp,lp) | shr1(cp,rp)
           | cm2 | cp2;

    comb[2 * w]     = c0;          // t-word
    comb[2 * w + 1] = di & ~er;    // boundary word
}

// ---- Kernel C: pure streaming elementwise + per-block partials ----
__global__ __launch_bounds__(256, 4) void combined_loss_kernel(
    const float* __restrict__ inp, const unsigned long long* __restrict__ comb,
    float* __restrict__ partials)
{
    const int tid = blockIdx.x * 256 + threadIdx.x;
    float s_focal = 0.f, s_inter = 0.f, s_p = 0.f, s_bw = 0.f;
    int s_tc = 0;

    #pragma unroll
    for (int it = 0; it < CITERS; it++) {
        const int f4 = tid + it * CTHREADS;
        const float4 v = ((const float4*)inp)[f4];
        const int wi = f4 >> 4;              // mask word index
        const int sh = (f4 & 15) * 4;        // nibble shift
        const unsigned long long tw = comb[2 * wi];
        const unsigned long long bw = comb[2 * wi + 1];
        unsigned int tb4 = (unsigned int)((tw >> sh) & 0xFULL);
        unsigned int bb4 = (unsigned int)((bw >> sh) & 0xFULL);
        s_tc += __popc(tb4);
        const float xs[4] = {v.x, v.y, v.z, v.w};
        #pragma unroll
        for (int k = 0; k < 4; k++) {
            float xi = xs[k];
            bool tpos = (tb4 >> k) & 1;
            float e  = __expf(-fabsf(xi));                  // exp(-|x|)
            float bce = fmaxf(xi, 0.f) - (tpos ? xi : 0.f) + __logf(1.f + e);
            float rden = __builtin_amdgcn_rcpf(1.f + e);
            float p = (xi >= 0.f ? 1.f : e) * rden;         // sigmoid
            float pt = tpos ? p : 1.f - p;                  // == exp(-bce)
            float om = 1.f - pt;
            s_focal += 0.25f * om * om * bce;
            s_p     += p;
            s_inter += tpos ? p : 0.f;
            float wgt = ((bb4 >> k) & 1) ? 6.0f : 1.0f;     // 1 + THETA*boundary
            s_bw += bce * wgt;
        }
    }
    float s_t = (float)s_tc;

    // ---- Reduce: wave shuffle -> LDS -> per-block partial store (NO atomics) ----
    __shared__ float smem[4][5];
    const int wave = threadIdx.x >> 6;
    const int lane = threadIdx.x & 63;
    #pragma unroll
    for (int off = 32; off > 0; off >>= 1) {
        s_focal += __shfl_down(s_focal, off);
        s_inter += __shfl_down(s_inter, off);
        s_p     += __shfl_down(s_p,     off);
        s_t     += __shfl_down(s_t,     off);
        s_bw    += __shfl_down(s_bw,    off);
    }
    if (lane == 0) {
        smem[wave][0] = s_focal; smem[wave][1] = s_inter; smem[wave][2] = s_p;
        smem[wave][3] = s_t;     smem[wave][4] = s_bw;
    }
    __syncthreads();
    if (threadIdx.x < 5) {
        float a = smem[0][threadIdx.x] + smem[1][threadIdx.x]
                + smem[2][threadIdx.x] + smem[3][threadIdx.x];
        partials[blockIdx.x * 8 + threadIdx.x] = a;
    }
}

// ---- Finalize: reduce NBLK_C partial slots, compute final scalar ----
__global__ __launch_bounds__(256) void finalize_kernel(
    const float* __restrict__ partials, float* __restrict__ out)
{
    __shared__ float smem[4][5];
    float a0 = 0.f, a1 = 0.f, a2 = 0.f, a3 = 0.f, a4 = 0.f;
    for (int b = threadIdx.x; b < NBLK_C; b += 256) {
        const float* s = partials + b * 8;
        a0 += s[0]; a1 += s[1]; a2 += s[2]; a3 += s[3]; a4 += s[4];
    }
    #pragma unroll
    for (int off = 32; off > 0; off >>= 1) {
        a0 += __shfl_down(a0, off);
        a1 += __shfl_down(a1, off);
        a2 += __shfl_down(a2, off);
        a3 += __shfl_down(a3, off);
        a4 += __shfl_down(a4, off);
    }
    int wave = threadIdx.x >> 6;
    int lane = threadIdx.x & 63;
    if (lane == 0) {
        smem[wave][0] = a0; smem[wave][1] = a1; smem[wave][2] = a2;
        smem[wave][3] = a3; smem[wave][4] = a4;
    }
    __syncthreads();
    if (threadIdx.x == 0) {
        double b0 = 0, b1 = 0, b2 = 0, b3 = 0, b4 = 0;
        #pragma unroll
        for (int w = 0; w < 4; w++) {
            b0 += smem[w][0]; b1 += smem[w][1]; b2 += smem[w][2];
            b3 += smem[w][3]; b4 += smem[w][4];
        }
        double invN = 1.0 / (double)(NIMG * HW);
        double focal_loss = b0 * invN;
        double dice = (2.0 * b1 + 1e-6) / (b2 + b3 + 1e-6);
        double boundary_loss = b4 * invN;
        out[0] = (float)(0.3 * focal_loss + 0.4 * (1.0 - dice) + 0.3 * boundary_loss);
    }
}

extern "C" void kernel_launch(void* const* d_in, const int* in_sizes, int n_in,
                              void* d_out, int out_size, void* d_ws, size_t ws_size,
                              hipStream_t stream) {
    const float* inp = (const float*)d_in[0];
    const float* tgt = (const float*)d_in[1];
    float* out = (float*)d_out;
    char* ws = (char*)d_ws;
    float* partials = (float*)ws;
    unsigned long long* tmask = (unsigned long long*)(ws + (1u << 20));
    unsigned long long* comb  = (unsigned long long*)(ws + (4u << 20));

    mask_kernel<<<NBLK_A, 256, 0, stream>>>(tgt, tmask);
    boundary_kernel<<<NBLK_B, 256, 0, stream>>>(tmask, comb);
    combined_loss_kernel<<<NBLK_C, 256, 0, stream>>>(inp, comb, partials);
    finalize_kernel<<<1, 256, 0, stream>>>(partials, out);
}